// Round 14
// baseline (256.737 us; speedup 1.0000x reference)
//
#include <hip/hip_runtime.h>
#include <math.h>

#define HID   2048
#define NEXP  64
#define NTOK  16384
#define SBLK  64      // sinkhorn blocks
#define TOLF  1e-4f
#define EPSF  1e-8f

typedef _Float16 f16x8 __attribute__((ext_vector_type(8)));
typedef float    f32x4 __attribute__((ext_vector_type(4)));

#define BSTRIDE 40               // f16 per LDS B row (32 data + 8 pad)
#define BUFELTS (8 * 64 * BSTRIDE)   // 4 wk x 2(h/l) x 64 rows x 40 = 20480 f16
#define LEAFSTRIDE 32            // ints (128 B) between barrier counters

// ---------------------------------------------------------------------------
// Kernel 0: split W (64x2048 fp32) into Wh + Wl*2048 (f16). Restored as a
// separate dispatch (R14): R9's fold forced fp32 W staging in the gemm loop
// -- each staging instr touches 2 lines/row (4x16B pieces, 32B apart) = 16K
// W line-touches/CU vs 4K for f16 staging (~8.7us at 1.7cyc/line), plus
// in-loop cvt8 VALU. R9's apparent win was the barrier change masking this.
// Also zeroes the 10 tree-barrier counter slots.
// f16x3 trick: x@W ~= xh@Wh + (xh@Wl' + xl'@Wh)/2048, residuals exact
// (Sterbenz); identical conversion math -> bitwise-identical L.
// ---------------------------------------------------------------------------
__global__ __launch_bounds__(256) void convert_w(const float* __restrict__ W,
                                                 _Float16* __restrict__ Wh,
                                                 _Float16* __restrict__ Wl,
                                                 int* __restrict__ cnt) {
    if (blockIdx.x == 0 && threadIdx.x < 10) cnt[threadIdx.x * LEAFSTRIDE] = 0;
    const int i = ((int)blockIdx.x * 256 + (int)threadIdx.x) * 8;
    const float4 w0 = *(const float4*)(W + i);
    const float4 w1 = *(const float4*)(W + i + 4);
    float v[8] = {w0.x, w0.y, w0.z, w0.w, w1.x, w1.y, w1.z, w1.w};
    f16x8 h, l;
#pragma unroll
    for (int j = 0; j < 8; ++j) {
        const _Float16 hh = (_Float16)v[j];
        h[j] = hh;
        l[j] = (_Float16)((v[j] - (float)hh) * 2048.0f);
    }
    *(f16x8*)(Wh + i) = h;
    *(f16x8*)(Wl + i) = l;
}

// ---------------------------------------------------------------------------
// Kernel 1: f16x3 MFMA logits, double-buffered LDS B, tail-issue schedule
// (R10 structure) + f16 W staging (R8 indexing, proven): thread owns
// (sa, srow, shalf); its two 16B loads land in the SAME 64B line per row ->
// 4K W line-touches/CU (was 16K fp32). No in-loop W conversion.
// Grid = 256 x 1024 thr (16 waves = 4 token-groups x 4 k-slices).
// Accumulation order unchanged -> bitwise-identical L.
// ---------------------------------------------------------------------------
__global__ __launch_bounds__(1024, 4) void gemm_mfma(const float* __restrict__ x,
                                                     const _Float16* __restrict__ Wh,
                                                     const _Float16* __restrict__ Wl,
                                                     float* __restrict__ L) {
    // 80 KB static LDS: two 40960 B B-buffers during the loop,
    // red[16][1024] f32 (64 KB) in the epilogue (aliased after final barrier).
    __shared__ __align__(16) char smem[81920];
    _Float16* Bs0 = (_Float16*)smem;
    _Float16* Bs1 = Bs0 + BUFELTS;
    float*    red = (float*)smem;

    const int tid    = (int)threadIdx.x;
    const int waveid = tid >> 6;       // 0..15
    const int wt     = waveid >> 2;    // token group 0..3 (16 tokens each)
    const int wk     = waveid & 3;     // k-slice 0..3 (512 k each)
    const int lane   = tid & 63;
    const int lo     = lane & 15;      // token row (A) / expert col (D)
    const int hi     = lane >> 4;      // k-block 0..3
    const int t0     = (int)blockIdx.x * 64;
    const int kb     = wk * 512;

    // f16 staging (R8 mapping): gt 0..255 -> sa (Wh/Wl), srow, shalf.
    const int gt    = wt * 64 + lane;
    const int sa    = gt >> 7;         // 0 = Wh, 1 = Wl
    const int srow  = (gt & 127) >> 1; // 0..63
    const int shalf = (gt & 1) * 16;   // 0 or 16 (f16)
    const _Float16* sgp = (sa ? Wl : Wh) + (size_t)srow * HID + kb + shalf;
    const int swbase = ((wk * 2 + sa) * 64 + srow) * BSTRIDE + shalf;

    const float* xp = x + (size_t)(t0 + wt * 16 + lo) * HID + kb + hi * 8;

    f32x4 acc_hh[4], acc_hl[4];
#pragma unroll
    for (int n = 0; n < 4; ++n) {
        acc_hh[n] = f32x4{0.f, 0.f, 0.f, 0.f};
        acc_hl[n] = f32x4{0.f, 0.f, 0.f, 0.f};
    }

    // ---- prologue: chunks 0,1 staged; A chunk0 (cur) + chunk1 (nxt);
    //      staging regs primed with chunk 2 BEFORE the first barrier.
    f16x8 sr0 = *(const f16x8*)(sgp);
    f16x8 sr1 = *(const f16x8*)(sgp + 8);
    {
        const f16x8 t2 = *(const f16x8*)(sgp + 32);
        const f16x8 t3 = *(const f16x8*)(sgp + 40);
        *(f16x8*)&Bs0[swbase]     = sr0;
        *(f16x8*)&Bs0[swbase + 8] = sr1;
        *(f16x8*)&Bs1[swbase]     = t2;
        *(f16x8*)&Bs1[swbase + 8] = t3;
    }
    float4 a0c = *(const float4*)(xp);
    float4 a1c = *(const float4*)(xp + 4);
    float4 a0n = *(const float4*)(xp + 32);
    float4 a1n = *(const float4*)(xp + 36);
    sr0 = *(const f16x8*)(sgp + 64);    // chunk 2 staging (written tail c=0)
    sr1 = *(const f16x8*)(sgp + 72);
    __syncthreads();

#pragma unroll 2
    for (int c = 0; c < 16; ++c) {
        // ---- compute phase: NO global issues here ----
        const _Float16* Bc = (c & 1) ? Bs1 : Bs0;
        f16x8 bh[4], bl[4];
#pragma unroll
        for (int n = 0; n < 4; ++n) {
            bh[n] = *(const f16x8*)&Bc[((wk * 2 + 0) * 64 + lo + n * 16) * BSTRIDE + hi * 8];
            bl[n] = *(const f16x8*)&Bc[((wk * 2 + 1) * 64 + lo + n * 16) * BSTRIDE + hi * 8];
        }

        // split current A chunk: xh (RTN) + xl*2048 (residual exact)
        f16x8 ah, al;
        const float av[8] = {a0c.x, a0c.y, a0c.z, a0c.w, a1c.x, a1c.y, a1c.z, a1c.w};
#pragma unroll
        for (int j = 0; j < 8; ++j) {
            const _Float16 hh = (_Float16)av[j];
            ah[j] = hh;
            al[j] = (_Float16)((av[j] - (float)hh) * 2048.0f);
        }

        // 12 MFMA; dependent acc_hl pairs separated by independent MFMAs
#pragma unroll
        for (int n = 0; n < 4; ++n)
            acc_hh[n] = __builtin_amdgcn_mfma_f32_16x16x32_f16(ah, bh[n], acc_hh[n], 0, 0, 0);
#pragma unroll
        for (int n = 0; n < 4; ++n)
            acc_hl[n] = __builtin_amdgcn_mfma_f32_16x16x32_f16(ah, bl[n], acc_hl[n], 0, 0, 0);
#pragma unroll
        for (int n = 0; n < 4; ++n)
            acc_hl[n] = __builtin_amdgcn_mfma_f32_16x16x32_f16(al, bh[n], acc_hl[n], 0, 0, 0);

        __syncthreads();   // drains only loads issued in tail(c-1): >=1 phase old

        // ---- tail: writes + ALL global issues for the next chunks ----
        if (c + 2 < 16) {              // write chunk c+2 (regs loaded tail(c-1))
            _Float16* Bw = (c & 1) ? Bs1 : Bs0;
            *(f16x8*)&Bw[swbase]     = sr0;
            *(f16x8*)&Bw[swbase + 8] = sr1;
        }
        a0c = a0n; a1c = a1n;          // A chunk c+1 (issued tail(c-1))
        if (c + 2 < 16) {              // issue A chunk c+2
            a0n = *(const float4*)(xp + (c + 2) * 32);
            a1n = *(const float4*)(xp + (c + 2) * 32 + 4);
        }
        if (c + 3 < 16) {              // issue W chunk c+3 (written tail(c+1))
            sr0 = *(const f16x8*)(sgp + (c + 3) * 32);
            sr1 = *(const f16x8*)(sgp + (c + 3) * 32 + 8);
        }
    }

    // epilogue: per-wave partials -> red (aliases B buffers; barriered)
#pragma unroll
    for (int n = 0; n < 4; ++n)
#pragma unroll
        for (int r = 0; r < 4; ++r)
            red[waveid * 1024 + n * 256 + r * 64 + lane] =
                acc_hh[n][r] + acc_hl[n][r] * (1.0f / 2048.0f);
    __syncthreads();

    // cross-wk reduce + coalesced write (unchanged mapping)
    {
        const int o      = tid * 4;
        const int t_loc  = o >> 6;
        const int e      = o & 63;
        const int wt_src = t_loc >> 4;
        const int tl     = t_loc & 15;
        const int idx    = (e >> 4) * 256 + (tl & 3) * 64 + (tl >> 2) * 16 + (e & 15);
        float4 s = *(const float4*)&red[(wt_src * 4 + 0) * 1024 + idx];
#pragma unroll
        for (int q = 1; q < 4; ++q) {
            const float4 v = *(const float4*)&red[(wt_src * 4 + q) * 1024 + idx];
            s.x += v.x; s.y += v.y; s.z += v.z; s.w += v.w;
        }
        *(float4*)(L + (size_t)(t0 + t_loc) * NEXP + e) = s;
    }
}

// ---------------------------------------------------------------------------
// wave-wide f32 sum via DPP (VALU-only). row_shr 1/2/4/8 within 16-lane rows,
// row_bcast15/31 merge rows; lane 63 holds total; readlane -> wave-uniform.
// ---------------------------------------------------------------------------
__device__ __forceinline__ float wave_sum64(float v) {
    int x;
    float t;
    x = __builtin_bit_cast(int, v);
    t = __builtin_bit_cast(float, __builtin_amdgcn_update_dpp(0, x, 0x111, 0xf, 0xf, true)); v += t;
    x = __builtin_bit_cast(int, v);
    t = __builtin_bit_cast(float, __builtin_amdgcn_update_dpp(0, x, 0x112, 0xf, 0xf, true)); v += t;
    x = __builtin_bit_cast(int, v);
    t = __builtin_bit_cast(float, __builtin_amdgcn_update_dpp(0, x, 0x114, 0xf, 0xf, true)); v += t;
    x = __builtin_bit_cast(int, v);
    t = __builtin_bit_cast(float, __builtin_amdgcn_update_dpp(0, x, 0x118, 0xf, 0xf, true)); v += t;
    x = __builtin_bit_cast(int, v);
    t = __builtin_bit_cast(float, __builtin_amdgcn_update_dpp(0, x, 0x142, 0xa, 0xf, true)); v += t;
    x = __builtin_bit_cast(int, v);
    t = __builtin_bit_cast(float, __builtin_amdgcn_update_dpp(0, x, 0x143, 0xc, 0xf, true)); v += t;
    return __builtin_bit_cast(float, __builtin_amdgcn_readlane(__builtin_bit_cast(int, v), 63));
}

// ---------------------------------------------------------------------------
// Tree grid barrier (R10 structure, unchanged). 8 padded leaf counters ->
// root -> generation flag; relaxed spin with periodic acquire. Counters
// monotonic, zeroed by convert_w (dispatch boundary = release). Consumer
// kernel is a PLAIN launch (R13, -19.6us): co-residency of 64 blocks is
// guaranteed by capacity (same resources ran cooperative for 5 rounds);
// failure mode = visible hang, not silent corruption.
// ---------------------------------------------------------------------------
__device__ __forceinline__ void grid_barrier(int* cnt, int g) {
    __syncthreads();
    if (threadIdx.x == 0) {
        int* leaf = cnt + ((int)blockIdx.x & 7) * LEAFSTRIDE;
        int* root = cnt + 8 * LEAFSTRIDE;
        int* gen  = cnt + 9 * LEAFSTRIDE;
        const int old = __hip_atomic_fetch_add(leaf, 1, __ATOMIC_ACQ_REL, __HIP_MEMORY_SCOPE_AGENT);
        if ((old & 7) == 7) {                 // 8th arrival of this generation
            const int r = __hip_atomic_fetch_add(root, 1, __ATOMIC_ACQ_REL, __HIP_MEMORY_SCOPE_AGENT);
            if ((r & 7) == 7)                 // last leaf of this generation
                __hip_atomic_store(gen, g + 1, __ATOMIC_RELEASE, __HIP_MEMORY_SCOPE_AGENT);
        }
        int it = 0;
        for (;;) {
            int v = __hip_atomic_load(gen, __ATOMIC_RELAXED, __HIP_MEMORY_SCOPE_AGENT);
            if (v >= g + 1) break;
            if ((++it & 7) == 0) {
                v = __hip_atomic_load(gen, __ATOMIC_ACQUIRE, __HIP_MEMORY_SCOPE_AGENT);
                if (v >= g + 1) break;
            }
            __builtin_amdgcn_s_sleep(1);
        }
        (void)__hip_atomic_load(gen, __ATOMIC_ACQUIRE, __HIP_MEMORY_SCOPE_AGENT);
    }
    __syncthreads();
}

// ---------------------------------------------------------------------------
// Kernel 2: sinkhorn + top-2 + softmax gather. Identical math to R7-R13
// (bit-identical iterates). Plain launch. Grid = 64 blocks x 1024 threads.
// Wave w owns tokens b*256+w*16..+15; lane = expert. cost in registers.
// ---------------------------------------------------------------------------
__global__ __launch_bounds__(1024) void sinkhorn_router(const float* __restrict__ L,
                                                        float* __restrict__ colbuf,
                                                        int* __restrict__ cnt,
                                                        float* __restrict__ out,
                                                        int nh) {
    __shared__ float part[16][64];
    __shared__ float redq[64][17];
    __shared__ float d1s[64];
    __shared__ float err_s;

    const int b     = blockIdx.x;   // 0..63
    const int tid   = (int)threadIdx.x;
    const int w     = tid >> 6;     // wave 0..15
    const int lane  = tid & 63;     // expert index
    const int tbase = b * 256 + w * 16;

    float logit[16], cost[16], dreg[16];
#pragma unroll
    for (int j = 0; j < 16; ++j) {
        const int t = tbase + j;
        float l = L[(size_t)t * NEXP + lane];
        for (int h = 1; h < nh; ++h)
            l += L[(size_t)h * NTOK * NEXP + (size_t)t * NEXP + lane];
        logit[j] = l;
        cost[j]  = expf(l);
        dreg[j]  = 0.0f;
    }

    float d1l   = 1.0f;   // this lane's d1[e]
    float d1old = 1.0f;   // previous d1 (used by tid<64 for err)
    int   g     = 0;

    for (;;) {
        // ---- phase A: d0 per token (DPP reduce) + per-wave column partials
        float colacc = 0.0f;
#pragma unroll
        for (int j = 0; j < 16; ++j) {
            const float s = wave_sum64(d1l * cost[j]);   // wave-uniform
            const float d0 = (1.0f / 16384.0f) / (s + EPSF);
            dreg[j] = d0;
            colacc = fmaf(d0, cost[j], colacc);
        }
        part[w][lane] = colacc;
        __syncthreads();

        float* cb = colbuf + (size_t)(g & 1) * (NEXP * SBLK);
        if (tid < 64) {
            float s = part[0][tid];
#pragma unroll
            for (int q = 1; q < 16; ++q) s += part[q][tid];
            cb[tid * SBLK + b] = s;     // reader-coalesced layout [e][b]
        }
        grid_barrier(cnt, g);

        // ---- phase B: cross-block column reduction, all 1024 threads ----
        {
            const int e = tid >> 4;     // 0..63
            const int q = tid & 15;     // 0..15 -> blocks q*4..q*4+3
            const float4 v = *(const float4*)(cb + e * SBLK + q * 4);
            redq[e][q] = (v.x + v.y) + (v.z + v.w);
        }
        __syncthreads();

        if (tid < 64) {
            float tot = redq[tid][0];
#pragma unroll
            for (int q = 1; q < 16; ++q) tot += redq[tid][q];
            const float d1n = (1.0f / 64.0f) / (tot + EPSF);
            float diff = fabsf(d1old - d1n);
#pragma unroll
            for (int m = 32; m; m >>= 1) diff += __shfl_xor(diff, m, 64);
            d1s[tid] = d1n;
            d1old    = d1n;
            if (tid == 0) err_s = diff * (1.0f / 64.0f);
        }
        __syncthreads();
        d1l = d1s[lane];
        const float err = err_s;
        ++g;
        if (!(err > TOLF) || g >= 512) break;   // matches while(err>tol); NaN stops
    }

    // ---- final: per token top-2 of d1*cost*d0, softmax gather ----
#pragma unroll 1
    for (int j = 0; j < 16; ++j) {
        const int t = tbase + j;
        const float v = (d1l * cost[j]) * dreg[j];

        float bv = v; int bi = lane;
#pragma unroll
        for (int m = 32; m; m >>= 1) {
            const float ov = __shfl_xor(bv, m, 64);
            const int   oi = __shfl_xor(bi, m, 64);
            if (ov > bv || (ov == bv && oi < bi)) { bv = ov; bi = oi; }
        }
        const int i1 = bi;

        const float v2 = (lane == i1) ? -INFINITY : v;
        float bv2 = v2; int bi2 = lane;
#pragma unroll
        for (int m = 32; m; m >>= 1) {
            const float ov = __shfl_xor(bv2, m, 64);
            const int   oi = __shfl_xor(bi2, m, 64);
            if (ov > bv2 || (ov == bv2 && oi < bi2)) { bv2 = ov; bi2 = oi; }
        }
        const int i2 = bi2;

        float mx = logit[j];
#pragma unroll
        for (int m = 32; m; m >>= 1) mx = fmaxf(mx, __shfl_xor(mx, m, 64));
        const float e = expf(logit[j] - mx);
        float se = e;
#pragma unroll
        for (int m = 32; m; m >>= 1) se += __shfl_xor(se, m, 64);

        const float p1 = __shfl(e, i1, 64) / se;
        const float p2 = __shfl(e, i2, 64) / se;

        if (lane == 0) {
            out[(size_t)t * 2 + 0] = p1;
            out[(size_t)t * 2 + 1] = p2;
            out[(size_t)NTOK * 2 + (size_t)t * 2 + 0] = (float)i1;
            out[(size_t)NTOK * 2 + (size_t)t * 2 + 1] = (float)i2;
        }
    }
}

// ---------------------------------------------------------------------------
// ws layout (4.78 MB total, well under the proven-available 8.4 MB minimum):
//   [0,       256KB)  Wh f16 [64][2048]
//   [256KB,   512KB)  Wl f16 [64][2048] (pre-scaled x2048)
//   [512KB,   4.5MB)  L  f32 [16384][64]
//   [4.5MB,  +32KB )  colbuf (2 x 64 x 64 f32, sinkhorn ping-pong)
//   [+1.25KB)         tree-barrier area (zeroed by convert_w each launch)
// ---------------------------------------------------------------------------
extern "C" void kernel_launch(void* const* d_in, const int* in_sizes, int n_in,
                              void* d_out, int out_size, void* d_ws, size_t ws_size,
                              hipStream_t stream) {
    const float* x = (const float*)d_in[0];
    const float* W = (const float*)d_in[1];
    float* out = (float*)d_out;

    _Float16* Wh = (_Float16*)d_ws;
    _Float16* Wl = Wh + (size_t)NEXP * HID;                  // +131072 elems
    float* L      = (float*)((char*)d_ws + 524288);
    float* colbuf = L + (size_t)NTOK * NEXP;
    int*   cnt    = (int*)(colbuf + 2 * NEXP * SBLK);

    convert_w<<<dim3(64), dim3(256), 0, stream>>>(W, Wh, Wl, cnt);
    gemm_mfma<<<dim3(256), dim3(1024), 0, stream>>>(x, Wh, Wl, L);
    sinkhorn_router<<<dim3(SBLK), dim3(1024), 0, stream>>>(L, colbuf, cnt, out, 1);
}

// Round 15
// 252.168 us; speedup vs baseline: 1.0181x; 1.0181x over previous
//
#include <hip/hip_runtime.h>
#include <math.h>

#define HID   2048
#define NEXP  64
#define NTOK  16384
#define SBLK  64      // sinkhorn blocks
#define TOLF  1e-4f
#define EPSF  1e-8f

typedef _Float16 f16x8 __attribute__((ext_vector_type(8)));
typedef float    f32x4 __attribute__((ext_vector_type(4)));

// ---------------------------------------------------------------------------
// f16x3 split of 8 fp32 values: h = RTN f32->f16, l = (v - h) * 2048 (exact
// residual, Sterbenz). Identical math every round -> bitwise-identical L.
// ---------------------------------------------------------------------------
__device__ __forceinline__ void cvt8(const float4 a, const float4 b,
                                     f16x8& h, f16x8& l) {
    const float v[8] = {a.x, a.y, a.z, a.w, b.x, b.y, b.z, b.w};
#pragma unroll
    for (int j = 0; j < 8; ++j) {
        const _Float16 hh = (_Float16)v[j];
        h[j] = hh;
        l[j] = (_Float16)((v[j] - (float)hh) * 2048.0f);
    }
}

// ---------------------------------------------------------------------------
// Kernel 1: f16x3 MFMA logits, double-buffered LDS B, tail-issue schedule,
// convert folded into staging (R13 configuration — measured best, 252.1us).
// R14 post-mortem: un-folding (separate convert_w + f16 staging) REGRESSED
// +4.6us — the fp32 staging cost is hidden under compute (tail-issued,
// W L2-resident), while a dispatch boundary is a guaranteed ~3-5us loss.
// Grid = 256 x 1024 thr (16 waves = 4 token-groups x 4 k-slices).
// Also zeroes the sinkhorn tree-barrier area (block 0).
// ---------------------------------------------------------------------------
#define BSTRIDE 40               // f16 per LDS B row (32 data + 8 pad)
#define BUFELTS (8 * 64 * BSTRIDE)   // 4 wk x 2(h/l) x 64 rows x 40 = 20480 f16
#define LEAFSTRIDE 32            // ints (128 B) between barrier counters

__global__ __launch_bounds__(1024, 4) void gemm_mfma(const float* __restrict__ x,
                                                     const float* __restrict__ W,
                                                     float* __restrict__ L,
                                                     int* __restrict__ cnt) {
    // 80 KB static LDS: two 40960 B B-buffers during the loop,
    // red[16][1024] f32 (64 KB) in the epilogue (aliased after final barrier).
    __shared__ __align__(16) char smem[81920];
    _Float16* Bs0 = (_Float16*)smem;
    _Float16* Bs1 = Bs0 + BUFELTS;
    float*    red = (float*)smem;

    const int tid = (int)threadIdx.x;
    if (blockIdx.x == 0 && tid < 10 * LEAFSTRIDE) cnt[tid] = 0;  // barrier area

    const int waveid = tid >> 6;       // 0..15
    const int wt     = waveid >> 2;    // token group 0..3 (16 tokens each)
    const int wk     = waveid & 3;     // k-slice 0..3 (512 k each)
    const int lane   = tid & 63;
    const int lo     = lane & 15;      // token row (A) / expert col (D)
    const int hi     = lane >> 4;      // k-block 0..3
    const int t0     = (int)blockIdx.x * 64;
    const int kb     = wk * 512;

    // staging: group-local thread gt owns row srow, frag sfrag (8 fp32 in,
    // 8+8 f16 out to the h-row and l-row).
    const int gt    = wt * 64 + lane;
    const int srow  = gt >> 2;         // 0..63
    const int sfrag = gt & 3;          // 0..3 -> floats sfrag*8..+7
    const float* sgp = W + (size_t)srow * HID + kb + sfrag * 8;
    const int swh = ((wk * 2 + 0) * 64 + srow) * BSTRIDE + sfrag * 8;
    const int swl = ((wk * 2 + 1) * 64 + srow) * BSTRIDE + sfrag * 8;

    const float* xp = x + (size_t)(t0 + wt * 16 + lo) * HID + kb + hi * 8;

    f32x4 acc_hh[4], acc_hl[4];
#pragma unroll
    for (int n = 0; n < 4; ++n) {
        acc_hh[n] = f32x4{0.f, 0.f, 0.f, 0.f};
        acc_hl[n] = f32x4{0.f, 0.f, 0.f, 0.f};
    }

    // ---- prologue: chunks 0,1 staged; A chunk0 (cur) + chunk1 (nxt);
    //      staging regs primed with chunk 2 BEFORE the first barrier (the
    //      one-time drain there is acceptable).
    float4 sv0 = *(const float4*)(sgp);
    float4 sv1 = *(const float4*)(sgp + 4);
    {
        const float4 t2 = *(const float4*)(sgp + 32);
        const float4 t3 = *(const float4*)(sgp + 36);
        f16x8 h, l;
        cvt8(sv0, sv1, h, l);
        *(f16x8*)&Bs0[swh] = h;
        *(f16x8*)&Bs0[swl] = l;
        cvt8(t2, t3, h, l);
        *(f16x8*)&Bs1[swh] = h;
        *(f16x8*)&Bs1[swl] = l;
    }
    float4 a0c = *(const float4*)(xp);
    float4 a1c = *(const float4*)(xp + 4);
    float4 a0n = *(const float4*)(xp + 32);
    float4 a1n = *(const float4*)(xp + 36);
    sv0 = *(const float4*)(sgp + 64);   // chunk 2 staging (written tail c=0)
    sv1 = *(const float4*)(sgp + 68);
    __syncthreads();

#pragma unroll 2
    for (int c = 0; c < 16; ++c) {
        // ---- compute phase: NO global issues here ----
        const _Float16* Bc = (c & 1) ? Bs1 : Bs0;
        f16x8 bh[4], bl[4];
#pragma unroll
        for (int n = 0; n < 4; ++n) {
            bh[n] = *(const f16x8*)&Bc[((wk * 2 + 0) * 64 + lo + n * 16) * BSTRIDE + hi * 8];
            bl[n] = *(const f16x8*)&Bc[((wk * 2 + 1) * 64 + lo + n * 16) * BSTRIDE + hi * 8];
        }

        f16x8 ah, al;
        const float av[8] = {a0c.x, a0c.y, a0c.z, a0c.w, a1c.x, a1c.y, a1c.z, a1c.w};
#pragma unroll
        for (int j = 0; j < 8; ++j) {
            const _Float16 hh = (_Float16)av[j];
            ah[j] = hh;
            al[j] = (_Float16)((av[j] - (float)hh) * 2048.0f);
        }

#pragma unroll
        for (int n = 0; n < 4; ++n)
            acc_hh[n] = __builtin_amdgcn_mfma_f32_16x16x32_f16(ah, bh[n], acc_hh[n], 0, 0, 0);
#pragma unroll
        for (int n = 0; n < 4; ++n)
            acc_hl[n] = __builtin_amdgcn_mfma_f32_16x16x32_f16(ah, bl[n], acc_hl[n], 0, 0, 0);
#pragma unroll
        for (int n = 0; n < 4; ++n)
            acc_hl[n] = __builtin_amdgcn_mfma_f32_16x16x32_f16(al, bh[n], acc_hl[n], 0, 0, 0);

        __syncthreads();   // drains only loads issued in tail(c-1): >=1 phase old

        // ---- tail: writes + ALL global issues for the next chunks ----
        if (c + 2 < 16) {              // write chunk c+2 (sv issued tail(c-1))
            _Float16* Bw = (c & 1) ? Bs1 : Bs0;
            f16x8 h, l;
            cvt8(sv0, sv1, h, l);
            *(f16x8*)&Bw[swh] = h;
            *(f16x8*)&Bw[swl] = l;
        }
        a0c = a0n; a1c = a1n;          // A chunk c+1 (issued tail(c-1))
        if (c + 2 < 16) {              // issue A chunk c+2
            a0n = *(const float4*)(xp + (c + 2) * 32);
            a1n = *(const float4*)(xp + (c + 2) * 32 + 4);
        }
        if (c + 3 < 16) {              // issue W chunk c+3 (written tail(c+1))
            sv0 = *(const float4*)(sgp + (c + 3) * 32);
            sv1 = *(const float4*)(sgp + (c + 3) * 32 + 4);
        }
    }

    // epilogue: per-wave partials -> red (aliases B buffers; barriered)
#pragma unroll
    for (int n = 0; n < 4; ++n)
#pragma unroll
        for (int r = 0; r < 4; ++r)
            red[waveid * 1024 + n * 256 + r * 64 + lane] =
                acc_hh[n][r] + acc_hl[n][r] * (1.0f / 2048.0f);
    __syncthreads();

    // cross-wk reduce + coalesced write (unchanged mapping)
    {
        const int o      = tid * 4;
        const int t_loc  = o >> 6;
        const int e      = o & 63;
        const int wt_src = t_loc >> 4;
        const int tl     = t_loc & 15;
        const int idx    = (e >> 4) * 256 + (tl & 3) * 64 + (tl >> 2) * 16 + (e & 15);
        float4 s = *(const float4*)&red[(wt_src * 4 + 0) * 1024 + idx];
#pragma unroll
        for (int q = 1; q < 4; ++q) {
            const float4 v = *(const float4*)&red[(wt_src * 4 + q) * 1024 + idx];
            s.x += v.x; s.y += v.y; s.z += v.z; s.w += v.w;
        }
        *(float4*)(L + (size_t)(t0 + t_loc) * NEXP + e) = s;
    }
}

// ---------------------------------------------------------------------------
// wave-wide f32 sum via DPP (VALU-only). row_shr 1/2/4/8 within 16-lane rows,
// row_bcast15/31 merge rows; lane 63 holds total; readlane -> wave-uniform.
// ---------------------------------------------------------------------------
__device__ __forceinline__ float wave_sum64(float v) {
    int x;
    float t;
    x = __builtin_bit_cast(int, v);
    t = __builtin_bit_cast(float, __builtin_amdgcn_update_dpp(0, x, 0x111, 0xf, 0xf, true)); v += t;
    x = __builtin_bit_cast(int, v);
    t = __builtin_bit_cast(float, __builtin_amdgcn_update_dpp(0, x, 0x112, 0xf, 0xf, true)); v += t;
    x = __builtin_bit_cast(int, v);
    t = __builtin_bit_cast(float, __builtin_amdgcn_update_dpp(0, x, 0x114, 0xf, 0xf, true)); v += t;
    x = __builtin_bit_cast(int, v);
    t = __builtin_bit_cast(float, __builtin_amdgcn_update_dpp(0, x, 0x118, 0xf, 0xf, true)); v += t;
    x = __builtin_bit_cast(int, v);
    t = __builtin_bit_cast(float, __builtin_amdgcn_update_dpp(0, x, 0x142, 0xa, 0xf, true)); v += t;
    x = __builtin_bit_cast(int, v);
    t = __builtin_bit_cast(float, __builtin_amdgcn_update_dpp(0, x, 0x143, 0xc, 0xf, true)); v += t;
    return __builtin_bit_cast(float, __builtin_amdgcn_readlane(__builtin_bit_cast(int, v), 63));
}

// ---------------------------------------------------------------------------
// Tree grid barrier (R10 structure). 8 padded leaf counters -> root ->
// generation flag; relaxed spin with periodic acquire. Counters monotonic,
// zeroed by gemm block 0 (dispatch boundary = release). Consumer kernel is
// a PLAIN launch (R13, -19.6us): co-residency of 64 blocks is guaranteed by
// capacity (same resources ran cooperative for 5 rounds); failure mode =
// visible hang, not silent corruption.
// ---------------------------------------------------------------------------
__device__ __forceinline__ void grid_barrier(int* cnt, int g) {
    __syncthreads();
    if (threadIdx.x == 0) {
        int* leaf = cnt + ((int)blockIdx.x & 7) * LEAFSTRIDE;
        int* root = cnt + 8 * LEAFSTRIDE;
        int* gen  = cnt + 9 * LEAFSTRIDE;
        const int old = __hip_atomic_fetch_add(leaf, 1, __ATOMIC_ACQ_REL, __HIP_MEMORY_SCOPE_AGENT);
        if ((old & 7) == 7) {                 // 8th arrival of this generation
            const int r = __hip_atomic_fetch_add(root, 1, __ATOMIC_ACQ_REL, __HIP_MEMORY_SCOPE_AGENT);
            if ((r & 7) == 7)                 // last leaf of this generation
                __hip_atomic_store(gen, g + 1, __ATOMIC_RELEASE, __HIP_MEMORY_SCOPE_AGENT);
        }
        int it = 0;
        for (;;) {
            int v = __hip_atomic_load(gen, __ATOMIC_RELAXED, __HIP_MEMORY_SCOPE_AGENT);
            if (v >= g + 1) break;
            if ((++it & 7) == 0) {
                v = __hip_atomic_load(gen, __ATOMIC_ACQUIRE, __HIP_MEMORY_SCOPE_AGENT);
                if (v >= g + 1) break;
            }
            __builtin_amdgcn_s_sleep(1);
        }
        (void)__hip_atomic_load(gen, __ATOMIC_ACQUIRE, __HIP_MEMORY_SCOPE_AGENT);
    }
    __syncthreads();
}

// ---------------------------------------------------------------------------
// Kernel 2: sinkhorn + top-2 + softmax gather. Identical math to R7-R14
// (bit-identical iterates). Plain launch. Grid = 64 blocks x 1024 threads.
// Wave w owns tokens b*256+w*16..+15; lane = expert. cost in registers.
// ---------------------------------------------------------------------------
__global__ __launch_bounds__(1024) void sinkhorn_router(const float* __restrict__ L,
                                                        float* __restrict__ colbuf,
                                                        int* __restrict__ cnt,
                                                        float* __restrict__ out,
                                                        int nh) {
    __shared__ float part[16][64];
    __shared__ float redq[64][17];
    __shared__ float d1s[64];
    __shared__ float err_s;

    const int b     = blockIdx.x;   // 0..63
    const int tid   = (int)threadIdx.x;
    const int w     = tid >> 6;     // wave 0..15
    const int lane  = tid & 63;     // expert index
    const int tbase = b * 256 + w * 16;

    float logit[16], cost[16], dreg[16];
#pragma unroll
    for (int j = 0; j < 16; ++j) {
        const int t = tbase + j;
        float l = L[(size_t)t * NEXP + lane];
        for (int h = 1; h < nh; ++h)
            l += L[(size_t)h * NTOK * NEXP + (size_t)t * NEXP + lane];
        logit[j] = l;
        cost[j]  = expf(l);
        dreg[j]  = 0.0f;
    }

    float d1l   = 1.0f;   // this lane's d1[e]
    float d1old = 1.0f;   // previous d1 (used by tid<64 for err)
    int   g     = 0;

    for (;;) {
        // ---- phase A: d0 per token (DPP reduce) + per-wave column partials
        float colacc = 0.0f;
#pragma unroll
        for (int j = 0; j < 16; ++j) {
            const float s = wave_sum64(d1l * cost[j]);   // wave-uniform
            const float d0 = (1.0f / 16384.0f) / (s + EPSF);
            dreg[j] = d0;
            colacc = fmaf(d0, cost[j], colacc);
        }
        part[w][lane] = colacc;
        __syncthreads();

        float* cb = colbuf + (size_t)(g & 1) * (NEXP * SBLK);
        if (tid < 64) {
            float s = part[0][tid];
#pragma unroll
            for (int q = 1; q < 16; ++q) s += part[q][tid];
            cb[tid * SBLK + b] = s;     // reader-coalesced layout [e][b]
        }
        grid_barrier(cnt, g);

        // ---- phase B: cross-block column reduction, all 1024 threads ----
        {
            const int e = tid >> 4;     // 0..63
            const int q = tid & 15;     // 0..15 -> blocks q*4..q*4+3
            const float4 v = *(const float4*)(cb + e * SBLK + q * 4);
            redq[e][q] = (v.x + v.y) + (v.z + v.w);
        }
        __syncthreads();

        if (tid < 64) {
            float tot = redq[tid][0];
#pragma unroll
            for (int q = 1; q < 16; ++q) tot += redq[tid][q];
            const float d1n = (1.0f / 64.0f) / (tot + EPSF);
            float diff = fabsf(d1old - d1n);
#pragma unroll
            for (int m = 32; m; m >>= 1) diff += __shfl_xor(diff, m, 64);
            d1s[tid] = d1n;
            d1old    = d1n;
            if (tid == 0) err_s = diff * (1.0f / 64.0f);
        }
        __syncthreads();
        d1l = d1s[lane];
        const float err = err_s;
        ++g;
        if (!(err > TOLF) || g >= 512) break;   // matches while(err>tol); NaN stops
    }

    // ---- final: per token top-2 of d1*cost*d0, softmax gather ----
#pragma unroll 1
    for (int j = 0; j < 16; ++j) {
        const int t = tbase + j;
        const float v = (d1l * cost[j]) * dreg[j];

        float bv = v; int bi = lane;
#pragma unroll
        for (int m = 32; m; m >>= 1) {
            const float ov = __shfl_xor(bv, m, 64);
            const int   oi = __shfl_xor(bi, m, 64);
            if (ov > bv || (ov == bv && oi < bi)) { bv = ov; bi = oi; }
        }
        const int i1 = bi;

        const float v2 = (lane == i1) ? -INFINITY : v;
        float bv2 = v2; int bi2 = lane;
#pragma unroll
        for (int m = 32; m; m >>= 1) {
            const float ov = __shfl_xor(bv2, m, 64);
            const int   oi = __shfl_xor(bi2, m, 64);
            if (ov > bv2 || (ov == bv2 && oi < bi2)) { bv2 = ov; bi2 = oi; }
        }
        const int i2 = bi2;

        float mx = logit[j];
#pragma unroll
        for (int m = 32; m; m >>= 1) mx = fmaxf(mx, __shfl_xor(mx, m, 64));
        const float e = expf(logit[j] - mx);
        float se = e;
#pragma unroll
        for (int m = 32; m; m >>= 1) se += __shfl_xor(se, m, 64);

        const float p1 = __shfl(e, i1, 64) / se;
        const float p2 = __shfl(e, i2, 64) / se;

        if (lane == 0) {
            out[(size_t)t * 2 + 0] = p1;
            out[(size_t)t * 2 + 1] = p2;
            out[(size_t)NTOK * 2 + (size_t)t * 2 + 0] = (float)i1;
            out[(size_t)NTOK * 2 + (size_t)t * 2 + 1] = (float)i2;
        }
    }
}

// ---------------------------------------------------------------------------
// ws layout (4.25 MB total):
//   [0,      4.0MB)  L  f32 [16384][64]
//   [4.0MB, +32KB )  colbuf (2 x 64 x 64 f32, sinkhorn ping-pong)
//   [+1.25KB)        tree-barrier area: 8 leaves + root + gen, 128B-padded
//                    (zeroed by gemm block 0 each launch)
// ---------------------------------------------------------------------------
extern "C" void kernel_launch(void* const* d_in, const int* in_sizes, int n_in,
                              void* d_out, int out_size, void* d_ws, size_t ws_size,
                              hipStream_t stream) {
    const float* x = (const float*)d_in[0];
    const float* W = (const float*)d_in[1];
    float* out = (float*)d_out;

    float* L      = (float*)d_ws;
    float* colbuf = L + (size_t)NTOK * NEXP;
    int*   cnt    = (int*)(colbuf + 2 * NEXP * SBLK);

    gemm_mfma<<<dim3(256), dim3(1024), 0, stream>>>(x, W, L, cnt);

    // Plain launch (R13): nothing in the kernel uses cooperative semantics
    // since R7's custom barrier; 64 blocks trivially co-resident on 256 CUs.
    sinkhorn_router<<<dim3(SBLK), dim3(1024), 0, stream>>>(L, colbuf, cnt, out, 1);
}